// Round 3
// baseline (250.349 us; speedup 1.0000x reference)
//
#include <hip/hip_runtime.h>
#include <hip/hip_bf16.h>

// ContralateralAttention, round 15: r14 dataflow (barrier-free MFMA via direct-L2 B-operands)
// with the LDS layout bug fixed: As2/As3 now overlay the dead ctx_s region (smem+0, smem+4096)
// instead of overflowing past the array end. Total LDS stays 72KB -> 2 blocks/CU.
// ws layout (MB): Xbf [0,16) | wbf [16,17) | qkv [17,65) | ctx [65,81)

#define NTOK 32768

using bf16x8 = __attribute__((ext_vector_type(8))) short;
using f32x4  = __attribute__((ext_vector_type(4))) float;

__device__ __forceinline__ float b2f(short s) {
    unsigned u = ((unsigned)(unsigned short)s) << 16;
    union { unsigned u; float f; } c; c.u = u; return c.f;
}
__device__ __forceinline__ short f2b(float f) {
    __hip_bfloat16 h = __float2bfloat16(f);
    return *(short*)&h;
}
__device__ __forceinline__ void async_copy16(const void* g, void* l) {
    __builtin_amdgcn_global_load_lds(
        (const __attribute__((address_space(1))) unsigned int*)g,
        (__attribute__((address_space(3))) unsigned int*)l, 16, 0, 0);
}

// ---------------- prep: vectorized feat transpose+cast AND weight casts ----------------
__global__ __launch_bounds__(256) void prep_kernel(const float* __restrict__ feat,
                                                   const float* __restrict__ in_w,
                                                   const float* __restrict__ out_w,
                                                   const float* __restrict__ proj_w,
                                                   __hip_bfloat16* __restrict__ X,
                                                   __hip_bfloat16* __restrict__ wbf) {
    const int bid = blockIdx.x;
    const int tid = threadIdx.x;
    if (bid < 4096) {
        __shared__ float tile[32][68];
        const int b   = bid >> 9;
        const int rem = bid & 511;
        const int sp0 = (rem & 63) * 64;
        const int c0  = (rem >> 6) * 32;
        #pragma unroll
        for (int u = 0; u < 2; ++u) {
            const int idx = tid + u * 256;      // 0..511
            const int cl = idx >> 4;            // 0..31
            const int sq = (idx & 15) * 4;      // 0..60
            const float4 v = *(const float4*)(feat + ((size_t)(b * 256 + c0 + cl) << 12) + sp0 + sq);
            tile[cl][sq]     = v.x;
            tile[cl][sq + 1] = v.y;
            tile[cl][sq + 2] = v.z;
            tile[cl][sq + 3] = v.w;
        }
        __syncthreads();
        #pragma unroll
        for (int u = 0; u < 2; ++u) {
            const int idx = tid + u * 256;      // 0..511
            const int tok = idx >> 3;           // 0..63
            const int cq  = (idx & 7) * 4;      // 0..28
            short4 s;
            s.x = f2b(tile[cq][tok]);
            s.y = f2b(tile[cq + 1][tok]);
            s.z = f2b(tile[cq + 2][tok]);
            s.w = f2b(tile[cq + 3][tok]);
            *(short4*)(X + (size_t)(b * 4096 + sp0 + tok) * 256 + c0 + cq) = s;
        }
    } else {
        const int i4 = (bid - 4096) * 1024 + tid * 4;
        if (i4 < 196608) {
            const float4 v = *(const float4*)(in_w + i4);
            short4 s = {f2b(v.x), f2b(v.y), f2b(v.z), f2b(v.w)};
            *(short4*)(wbf + i4) = s;
        }
        if (i4 < 65536) {
            const float4 v = *(const float4*)(out_w + i4);
            short4 s = {f2b(v.x), f2b(v.y), f2b(v.z), f2b(v.w)};
            *(short4*)(wbf + 196608 + i4) = s;
        }
        if (i4 < 262144) {
            const float4 v = *(const float4*)(proj_w + i4);
            short4 s = {f2b(v.x), f2b(v.y), f2b(v.z), f2b(v.w)};
            *(short4*)(wbf + 262144 + i4) = s;
        }
    }
}

// ---------------- MFMA GEMM (qkv): 256 thr, M=128 x N=128, K=256 ----------------
// A-tile (X, unique per block) staged ONCE into 64KB LDS (swizzled); B (in_w, L2-resident,
// shared by all 1536 blocks) read directly as fragments. K-loop is barrier-free.
template <int KDIM, bool OUT_BF16>
__global__ __launch_bounds__(256) void mfma_gemm(const __hip_bfloat16* __restrict__ A,
                                                 const __hip_bfloat16* __restrict__ W,
                                                 const float* __restrict__ bias,
                                                 void* __restrict__ C, int Ntot) {
    __shared__ __align__(16) short As[128 * 256];   // 64 KB, full A-tile
    const int tid = threadIdx.x;
    const int m0 = blockIdx.x * 128;
    const int n0 = blockIdx.y * 128;
    const int wave = tid >> 6, lane = tid & 63;
    const int wm = (wave >> 1) * 64;
    const int wn = (wave & 1) * 64;
    const int fm = lane & 15;
    const int fq = lane >> 4;

    // stage full A-tile once: 4096 16B-chunks, 16 per thread, row-swizzled source
    #pragma unroll
    for (int v = 0; v < 16; ++v) {
        const int q = v * 256 + tid;
        const int r = q >> 5;                 // row 0..127
        const int sl = q & 31;                // stored slot
        const int gc = (sl & 24) | ((sl & 7) ^ (r & 7));
        async_copy16(A + (size_t)(m0 + r) * KDIM + gc * 8, &As[(v * 256 + wave * 64) * 8]);
    }
    __syncthreads();

    f32x4 acc[4][4] = {};
    #pragma unroll
    for (int k0 = 0; k0 < KDIM; k0 += 64) {
        #pragma unroll
        for (int kk = 0; kk < 2; ++kk) {
            const int jj = (k0 >> 3) + fq + kk * 4;
            bf16x8 af[4], bw[4];
            #pragma unroll
            for (int i = 0; i < 4; ++i) {
                const int row = wm + i * 16 + fm;
                const int sl = (jj & 24) | ((jj & 7) ^ (row & 7));
                af[i] = *(const bf16x8*)(&As[row * 256 + sl * 8]);
            }
            #pragma unroll
            for (int j = 0; j < 4; ++j) {
                const int row = n0 + wn + j * 16 + fm;
                bw[j] = *(const bf16x8*)(W + (size_t)row * KDIM + k0 + (fq + kk * 4) * 8);
            }
            #pragma unroll
            for (int i = 0; i < 4; ++i)
                #pragma unroll
                for (int j = 0; j < 4; ++j)
                    acc[i][j] = __builtin_amdgcn_mfma_f32_16x16x32_bf16(af[i], bw[j], acc[i][j], 0, 0, 0);
        }
    }
    #pragma unroll
    for (int j = 0; j < 4; ++j) {
        const int col = n0 + wn + j * 16 + fm;
        const float bv = bias[col];
        #pragma unroll
        for (int i = 0; i < 4; ++i) {
            #pragma unroll
            for (int r = 0; r < 4; ++r) {
                const int row = m0 + wm + i * 16 + fq * 4 + r;
                const float v = acc[i][j][r] + bv;
                if (OUT_BF16)
                    ((__hip_bfloat16*)C)[(size_t)row * Ntot + col] = __float2bfloat16(v);
                else
                    ((float*)C)[(size_t)row * Ntot + col] = v;
            }
        }
    }
}

// ---------------- sparse attention (r7 form, validated) ----------------
#define P0DY ((2u)|(2u<<3)|(2u<<6)|(2u<<9)|(2u<<12)|(1u<<15)|(1u<<18)|(1u<<21))
#define P0DX ((2u)|(1u<<3)|(3u<<6)|(0u<<9)|(4u<<12)|(2u<<15)|(1u<<18)|(3u<<21))
#define P1DY ((3u)|(3u<<3)|(3u<<6)|(0u<<9)|(4u<<12)|(2u<<15)|(2u<<18)|(2u<<21))
#define P1DX ((2u)|(1u<<3)|(3u<<6)|(2u<<9)|(2u<<12)|(2u<<15)|(2u<<18)|(2u<<21))

__global__ __launch_bounds__(256) void attn_kernel(const __hip_bfloat16* __restrict__ qkv,
                                                   __hip_bfloat16* __restrict__ ctx) {
    const int t = blockIdx.x * 4 + (threadIdx.x >> 6);
    const int lane = threadIdx.x & 63;
    const int n  = lane >> 3;
    const int cg = lane & 7;
    const int x6 = t & 63;
    const int yq = (t >> 6) & 63;
    const int b  = t >> 12;
    const int side = x6 >> 5;
    const int x = x6 & 31;

    bool valid[2];
    size_t kb[2];
    #pragma unroll
    for (int p = 0; p < 2; ++p) {
        const unsigned dyp = p ? P1DY : P0DY;
        const unsigned dxp = p ? P1DX : P0DX;
        const int sh = 3 * n;
        const int dy = (int)((dyp >> sh) & 7) - 2;
        const int dx = (int)((dxp >> sh) & 7) - 2;
        const int yy = yq + dy, xx = x + dx;
        valid[p] = (p == 0 || n < 5) && yy >= 0 && yy < 64 && xx >= 0 && xx < 32;
        const int xm = side ? (31 - xx) : (63 - xx);
        int tm = (b << 12) + (yy << 6) + xm;
        if (!valid[p]) tm = t;
        kb[p] = (size_t)tm * 768 + 256 + cg * 8;
    }
    const size_t qb = (size_t)t * 768 + cg * 8;
    const size_t ob = (size_t)t * 256;

    #pragma unroll
    for (int hp = 0; hp < 2; ++hp) {
        bf16x8 q8[2], k8[2][2], v8[2][2];
        #pragma unroll
        for (int hh = 0; hh < 2; ++hh) {
            const int h = hp * 2 + hh;
            q8[hh] = *(const bf16x8*)(qkv + qb + h * 64);
            #pragma unroll
            for (int p = 0; p < 2; ++p) {
                k8[hh][p] = *(const bf16x8*)(qkv + kb[p] + h * 64);
                v8[hh][p] = *(const bf16x8*)(qkv + kb[p] + h * 64 + 256);
            }
        }
        #pragma unroll
        for (int hh = 0; hh < 2; ++hh) {
            float sc[2];
            #pragma unroll
            for (int p = 0; p < 2; ++p) {
                float s = 0.f;
                #pragma unroll
                for (int j = 0; j < 8; ++j) s += b2f(q8[hh][j]) * b2f(k8[hh][p][j]);
                s += __shfl_xor(s, 1, 64);
                s += __shfl_xor(s, 2, 64);
                s += __shfl_xor(s, 4, 64);
                sc[p] = valid[p] ? s * 0.125f : -1e30f;
            }
            const float p0 = __expf(sc[0]);
            const float p1 = __expf(sc[1]);
            float l = p0 + p1;
            l += __shfl_xor(l, 8, 64);
            l += __shfl_xor(l, 16, 64);
            l += __shfl_xor(l, 32, 64);

            float o[8];
            #pragma unroll
            for (int j = 0; j < 8; ++j)
                o[j] = p0 * b2f(v8[hh][0][j]) + p1 * b2f(v8[hh][1][j]);
            float r4[4];
            #pragma unroll
            for (int i = 0; i < 4; ++i) {
                const float a = o[2 * i], bb = o[2 * i + 1];
                const float mine = (n & 1) ? bb : a;
                const float theirs = (n & 1) ? a : bb;
                r4[i] = mine + __shfl_xor(theirs, 8, 64);
            }
            float r2[2];
            #pragma unroll
            for (int i = 0; i < 2; ++i) {
                const float a = r4[2 * i], bb = r4[2 * i + 1];
                const float mine = (n & 2) ? bb : a;
                const float theirs = (n & 2) ? a : bb;
                r2[i] = mine + __shfl_xor(theirs, 16, 64);
            }
            float ov;
            {
                const float a = r2[0], bb = r2[1];
                const float mine = (n & 4) ? bb : a;
                const float theirs = (n & 4) ? a : bb;
                ov = mine + __shfl_xor(theirs, 32, 64);
            }
            const float rl = __builtin_amdgcn_rcpf(l);
            ctx[ob + (hp * 2 + hh) * 64 + cg * 8 + n] = __float2bfloat16(ov * rl);
        }
    }
}

// ---------------- fused: ctx2 = ctx@out_w^T+out_b (in LDS), then proj+LN+ReLU+store ----------------
// r15: 512 thr / 8 waves (2M x 4N). CTX staged once; out_w/proj_w fragments direct from L2.
// Phase A: barrier-free K-loop. Phase B: 4 col-steps, 2 barriers each; As2/As3 overlay the
// dead ctx_s region. LDS 72KB -> 2 blocks/CU.
__global__ __launch_bounds__(512, 4) void proj_ln_fused(const __hip_bfloat16* __restrict__ X,
                                                        const __hip_bfloat16* __restrict__ CTX,
                                                        const __hip_bfloat16* __restrict__ W2,
                                                        const float* __restrict__ out_b,
                                                        const __hip_bfloat16* __restrict__ W,
                                                        const float* __restrict__ bias,
                                                        const float* __restrict__ ln_g,
                                                        const float* __restrict__ ln_b,
                                                        float* __restrict__ out) {
    __shared__ __align__(16) short smem[36864];   // 72 KB
    __shared__ float mu_s[64], inv_s[64];
    short* ctx_s = smem;           // 64 x 256 (32 KB), phase A only
    short* c2s   = smem + 16384;   // 64 x 256 (32 KB), persists through phase B
    short* As2   = smem;           // 64 x 64 (8 KB), |q-c2| tile — overlays dead ctx_s
    short* As3   = smem + 4096;    // 64 x 64 (8 KB), q*c2 tile  — overlays dead ctx_s
    const int tid = threadIdx.x;
    const int m0 = blockIdx.x * 64;
    const int b = m0 >> 12, sp0 = m0 & 4095;
    const int wave = tid >> 6, lane = tid & 63;
    const int wmh = (wave >> 2) * 32;   // M-half
    const int wn  = (wave & 3) * 64;    // N-quarter
    const int fm = lane & 15;
    const int fq = lane >> 4;

    // ---- stage CTX tile once (swizzled source, linear LDS) ----
    #pragma unroll
    for (int v = 0; v < 4; ++v) {
        const int q = v * 512 + tid;
        const int r = q >> 5;              // row 0..63
        const int sl = q & 31;
        const int gc = (sl & 24) | ((sl & 7) ^ (r & 7));
        async_copy16(CTX + (size_t)(m0 + r) * 256 + gc * 8, &ctx_s[(v * 512 + wave * 64) * 8]);
    }
    __syncthreads();

    // ---- phase A: ctx2 = ctx @ out_w^T, barrier-free K-loop, B direct from L2 ----
    {
        f32x4 acc2[2][4] = {};
        #pragma unroll
        for (int k0 = 0; k0 < 256; k0 += 64) {
            #pragma unroll
            for (int kk = 0; kk < 2; ++kk) {
                const int jj = (k0 >> 3) + fq + kk * 4;
                bf16x8 af[2], bw[4];
                #pragma unroll
                for (int i = 0; i < 2; ++i) {
                    const int row = wmh + i * 16 + fm;
                    const int sl = (jj & 24) | ((jj & 7) ^ (row & 7));
                    af[i] = *(const bf16x8*)(&ctx_s[row * 256 + sl * 8]);
                }
                #pragma unroll
                for (int j = 0; j < 4; ++j) {
                    const int row = wn + j * 16 + fm;
                    bw[j] = *(const bf16x8*)(W2 + (size_t)row * 256 + k0 + (fq + kk * 4) * 8);
                }
                #pragma unroll
                for (int i = 0; i < 2; ++i)
                    #pragma unroll
                    for (int j = 0; j < 4; ++j)
                        acc2[i][j] = __builtin_amdgcn_mfma_f32_16x16x32_bf16(af[i], bw[j], acc2[i][j], 0, 0, 0);
            }
        }
        // write c2 tile (bias added) into its own region; barrier after
        #pragma unroll
        for (int j = 0; j < 4; ++j) {
            const int col = wn + j * 16 + fm;
            const float bv = out_b[col];
            const int jch = col >> 3, cl = col & 7;
            #pragma unroll
            for (int i = 0; i < 2; ++i)
                #pragma unroll
                for (int rr = 0; rr < 4; ++rr) {
                    const int row = wmh + i * 16 + fq * 4 + rr;
                    const int slot = (jch & 24) | ((jch & 7) ^ (row & 7));
                    c2s[row * 256 + slot * 8 + cl] = f2b(acc2[i][j][rr] + bv);
                }
        }
    }
    __syncthreads();   // phase-A ctx_s reads done -> As2/As3 may overlay it

    // ---- phase B: proj over K=1024 = [q | c2 | |q-c2| | q*c2], B direct from L2 ----
    f32x4 acc[2][4] = {};
    for (int cbs = 0; cbs < 4; ++cbs) {
        const int cb = cbs * 64;
        // construction pre-loads (issued before barrier -> overlap prev MFMA burst)
        const int cr = tid >> 3;
        const int cs = (tid & 7) ^ (cr & 7);
        int4 qraw = *(const int4*)(X + (size_t)(m0 + cr) * 256 + cb + cs * 8);
        const int cjch = (cb >> 3) + cs;
        const int cslot = (cjch & 24) | ((cjch & 7) ^ (cr & 7));
        int4 craw = *(const int4*)(&c2s[cr * 256 + cslot * 8]);
        __syncthreads();               // prev col-step's As2/As3 reads complete
        {
            const short* qs = (const short*)&qraw;
            const short* cw = (const short*)&craw;
            short t2[8], t3[8];
            #pragma unroll
            for (int j = 0; j < 8; ++j) {
                const float qv = b2f(qs[j]), cv = b2f(cw[j]);
                t2[j] = f2b(fabsf(qv - cv));
                t3[j] = f2b(qv * cv);
            }
            *(int4*)(&As2[tid * 8]) = *(int4*)t2;
            *(int4*)(&As3[tid * 8]) = *(int4*)t3;
        }
        __syncthreads();               // As2/As3 ready
        #pragma unroll
        for (int g = 0; g < 4; ++g) {
            #pragma unroll
            for (int kk = 0; kk < 2; ++kk) {
                bf16x8 af[2], bw[4];
                #pragma unroll
                for (int j = 0; j < 4; ++j) {
                    const int row = wn + j * 16 + fm;
                    bw[j] = *(const bf16x8*)(W + (size_t)row * 1024 + g * 256 + cb + (fq + kk * 4) * 8);
                }
                #pragma unroll
                for (int i = 0; i < 2; ++i) {
                    const int row = wmh + i * 16 + fm;
                    if (g == 0) {
                        af[i] = *(const bf16x8*)(X + (size_t)(m0 + row) * 256 + cb + (fq + kk * 4) * 8);
                    } else if (g == 1) {
                        const int jj = (cb >> 3) + fq + kk * 4;
                        const int sl = (jj & 24) | ((jj & 7) ^ (row & 7));
                        af[i] = *(const bf16x8*)(&c2s[row * 256 + sl * 8]);
                    } else {
                        const short* Ag = (g == 2) ? As2 : As3;
                        af[i] = *(const bf16x8*)(&Ag[row * 64 + (((fq + kk * 4) ^ (row & 7)) * 8)]);
                    }
                }
                #pragma unroll
                for (int i = 0; i < 2; ++i)
                    #pragma unroll
                    for (int j = 0; j < 4; ++j)
                        acc[i][j] = __builtin_amdgcn_mfma_f32_16x16x32_bf16(af[i], bw[j], acc[i][j], 0, 0, 0);
            }
        }
    }
    __syncthreads();   // all c2s/As reads done before ys overlays the region

    // ---- epilogue: ys (bf16, stride 266) overlays smem head; LN; ReLU; store ----
    short* ys = smem;
    #pragma unroll
    for (int j = 0; j < 4; ++j) {
        const int col = wn + j * 16 + fm;
        const float bv = bias[col];
        #pragma unroll
        for (int i = 0; i < 2; ++i)
            #pragma unroll
            for (int r = 0; r < 4; ++r)
                ys[(wmh + i * 16 + fq * 4 + r) * 266 + col] = f2b(acc[i][j][r] + bv);
    }
    __syncthreads();
    {
        const int tt = tid >> 3, seg = tid & 7;   // 64 rows x 8 segs of 32
        float s = 0.f, ss = 0.f;
        #pragma unroll
        for (int j = 0; j < 32; ++j) {
            const float v = b2f(ys[tt * 266 + seg * 32 + j]);
            s += v; ss += v * v;
        }
        s += __shfl_xor(s, 1, 64);  ss += __shfl_xor(ss, 1, 64);
        s += __shfl_xor(s, 2, 64);  ss += __shfl_xor(ss, 2, 64);
        s += __shfl_xor(s, 4, 64);  ss += __shfl_xor(ss, 4, 64);
        if (seg == 0) {
            const float mu = s * (1.f / 256.f);
            const float var = ss * (1.f / 256.f) - mu * mu;
            mu_s[tt] = mu;
            inv_s[tt] = rsqrtf(var + 1e-5f);
        }
    }
    __syncthreads();
    {
        const int tl = tid & 63;
        const int j0 = tid >> 6;                  // 8 col-blocks of 32
        const float mu = mu_s[tl], inv = inv_s[tl];
        #pragma unroll
        for (int u = 0; u < 32; ++u) {
            const int j = j0 * 32 + u;
            const float v = (b2f(ys[tl * 266 + j]) - mu) * inv * ln_g[j] + ln_b[j];
            out[((size_t)(b * 256 + j) << 12) + sp0 + tl] = fmaxf(v, 0.f);
        }
    }
}

extern "C" void kernel_launch(void* const* d_in, const int* in_sizes, int n_in,
                              void* d_out, int out_size, void* d_ws, size_t ws_size,
                              hipStream_t stream) {
    (void)in_sizes; (void)n_in; (void)out_size; (void)ws_size;
    const float* feat   = (const float*)d_in[0];
    const float* in_w   = (const float*)d_in[1];
    const float* in_b   = (const float*)d_in[2];
    const float* out_w  = (const float*)d_in[3];
    const float* out_b  = (const float*)d_in[4];
    const float* proj_w = (const float*)d_in[5];
    const float* proj_b = (const float*)d_in[6];
    const float* ln_g   = (const float*)d_in[7];
    const float* ln_b   = (const float*)d_in[8];
    float* out = (float*)d_out;

    char* ws = (char*)d_ws;
    __hip_bfloat16* Xbf  = (__hip_bfloat16*)(ws);
    __hip_bfloat16* wbf  = (__hip_bfloat16*)(ws + (size_t)(16) * (1 << 20));
    __hip_bfloat16* qkv  = (__hip_bfloat16*)(ws + (size_t)(17) * (1 << 20));
    __hip_bfloat16* ctx  = (__hip_bfloat16*)(ws + (size_t)(65) * (1 << 20));
    __hip_bfloat16* in_wbf   = wbf;
    __hip_bfloat16* out_wbf  = wbf + 196608;
    __hip_bfloat16* proj_wbf = wbf + 262144;

    prep_kernel   <<<4352, 256, 0, stream>>>(feat, in_w, out_w, proj_w, Xbf, wbf);
    mfma_gemm<256, true><<<dim3(256, 6), 256, 0, stream>>>(Xbf, in_wbf, in_b, qkv, 768);
    attn_kernel   <<<NTOK / 4, 256, 0, stream>>>(qkv, ctx);
    proj_ln_fused <<<NTOK / 64, 512, 0, stream>>>(Xbf, ctx, out_wbf, out_b,
                                                  proj_wbf, proj_b, ln_g, ln_b, out);
}

// Round 4
// 201.157 us; speedup vs baseline: 1.2445x; 1.2445x over previous
//
#include <hip/hip_runtime.h>
#include <hip/hip_bf16.h>

// ContralateralAttention, round 16: 2-phase double-buffered staging (guide §T3 minimum recipe).
// Per K-step: {issue next-tile global_load_lds; compute current buffer; ONE __syncthreads()}.
// r15's direct-L2 B-fragments reverted (latency-bound: MfmaUtil 8.8%). proj g2/g3 derived
// A-fragments built in-register from LDS X-tile + c2s (elementwise; VALU overlaps MFMA).
// ws layout (MB): Xbf [0,16) | wbf [16,17) | qkv [17,65) | ctx [65,81)

#define NTOK 32768

using bf16x8 = __attribute__((ext_vector_type(8))) short;
using f32x4  = __attribute__((ext_vector_type(4))) float;

__device__ __forceinline__ float b2f(short s) {
    unsigned u = ((unsigned)(unsigned short)s) << 16;
    union { unsigned u; float f; } c; c.u = u; return c.f;
}
__device__ __forceinline__ short f2b(float f) {
    __hip_bfloat16 h = __float2bfloat16(f);
    return *(short*)&h;
}
__device__ __forceinline__ void async_copy16(const void* g, void* l) {
    __builtin_amdgcn_global_load_lds(
        (const __attribute__((address_space(1))) unsigned int*)g,
        (__attribute__((address_space(3))) unsigned int*)l, 16, 0, 0);
}

// ---------------- prep: vectorized feat transpose+cast AND weight casts ----------------
__global__ __launch_bounds__(256) void prep_kernel(const float* __restrict__ feat,
                                                   const float* __restrict__ in_w,
                                                   const float* __restrict__ out_w,
                                                   const float* __restrict__ proj_w,
                                                   __hip_bfloat16* __restrict__ X,
                                                   __hip_bfloat16* __restrict__ wbf) {
    const int bid = blockIdx.x;
    const int tid = threadIdx.x;
    if (bid < 4096) {
        __shared__ float tile[32][68];
        const int b   = bid >> 9;
        const int rem = bid & 511;
        const int sp0 = (rem & 63) * 64;
        const int c0  = (rem >> 6) * 32;
        #pragma unroll
        for (int u = 0; u < 2; ++u) {
            const int idx = tid + u * 256;      // 0..511
            const int cl = idx >> 4;            // 0..31
            const int sq = (idx & 15) * 4;      // 0..60
            const float4 v = *(const float4*)(feat + ((size_t)(b * 256 + c0 + cl) << 12) + sp0 + sq);
            tile[cl][sq]     = v.x;
            tile[cl][sq + 1] = v.y;
            tile[cl][sq + 2] = v.z;
            tile[cl][sq + 3] = v.w;
        }
        __syncthreads();
        #pragma unroll
        for (int u = 0; u < 2; ++u) {
            const int idx = tid + u * 256;      // 0..511
            const int tok = idx >> 3;           // 0..63
            const int cq  = (idx & 7) * 4;      // 0..28
            short4 s;
            s.x = f2b(tile[cq][tok]);
            s.y = f2b(tile[cq + 1][tok]);
            s.z = f2b(tile[cq + 2][tok]);
            s.w = f2b(tile[cq + 3][tok]);
            *(short4*)(X + (size_t)(b * 4096 + sp0 + tok) * 256 + c0 + cq) = s;
        }
    } else {
        const int i4 = (bid - 4096) * 1024 + tid * 4;
        if (i4 < 196608) {
            const float4 v = *(const float4*)(in_w + i4);
            short4 s = {f2b(v.x), f2b(v.y), f2b(v.z), f2b(v.w)};
            *(short4*)(wbf + i4) = s;
        }
        if (i4 < 65536) {
            const float4 v = *(const float4*)(out_w + i4);
            short4 s = {f2b(v.x), f2b(v.y), f2b(v.z), f2b(v.w)};
            *(short4*)(wbf + 196608 + i4) = s;
        }
        if (i4 < 262144) {
            const float4 v = *(const float4*)(proj_w + i4);
            short4 s = {f2b(v.x), f2b(v.y), f2b(v.z), f2b(v.w)};
            *(short4*)(wbf + 262144 + i4) = s;
        }
    }
}

// ---------------- MFMA GEMM (qkv): 256 thr, M=128 x N=128, BK=64, 2-phase dbuf ----------------
template <int KDIM, bool OUT_BF16>
__global__ __launch_bounds__(256) void mfma_gemm(const __hip_bfloat16* __restrict__ A,
                                                 const __hip_bfloat16* __restrict__ W,
                                                 const float* __restrict__ bias,
                                                 void* __restrict__ C, int Ntot) {
    __shared__ __align__(16) short As[2][128 * 64];   // 2 x 16 KB
    __shared__ __align__(16) short Bs[2][128 * 64];   // 2 x 16 KB
    const int tid = threadIdx.x;
    const int m0 = blockIdx.x * 128;
    const int n0 = blockIdx.y * 128;
    const int wave = tid >> 6, lane = tid & 63;
    const int wm = (wave >> 1) * 64;
    const int wn = (wave & 1) * 64;
    const int fm = lane & 15;
    const int fq = lane >> 4;

    // prologue: stage K-slice 0 into buffer 0
    #pragma unroll
    for (int v = 0; v < 4; ++v) {
        const int qb = v * 256 + wave * 64;
        const int q = qb + lane;
        const int r = q >> 3;
        const int cs = (q & 7) ^ (r & 7);
        async_copy16(A + (size_t)(m0 + r) * KDIM + cs * 8, &As[0][qb * 8]);
        async_copy16(W + (size_t)(n0 + r) * KDIM + cs * 8, &Bs[0][qb * 8]);
    }
    __syncthreads();

    f32x4 acc[4][4] = {};
    #pragma unroll
    for (int t = 0; t < KDIM / 64; ++t) {
        const int cur = t & 1;
        if (t + 1 < KDIM / 64) {                       // issue next-slice stage FIRST
            #pragma unroll
            for (int v = 0; v < 4; ++v) {
                const int qb = v * 256 + wave * 64;
                const int q = qb + lane;
                const int r = q >> 3;
                const int cs = (q & 7) ^ (r & 7);
                async_copy16(A + (size_t)(m0 + r) * KDIM + (t + 1) * 64 + cs * 8, &As[cur ^ 1][qb * 8]);
                async_copy16(W + (size_t)(n0 + r) * KDIM + (t + 1) * 64 + cs * 8, &Bs[cur ^ 1][qb * 8]);
            }
        }
        #pragma unroll
        for (int kk = 0; kk < 2; ++kk) {
            bf16x8 af[4], bw[4];
            #pragma unroll
            for (int i = 0; i < 4; ++i) {
                const int row = wm + i * 16 + fm;
                af[i] = *(const bf16x8*)(&As[cur][row * 64 + (((fq + kk * 4) ^ (fm & 7)) * 8)]);
            }
            #pragma unroll
            for (int j = 0; j < 4; ++j) {
                const int row = wn + j * 16 + fm;
                bw[j] = *(const bf16x8*)(&Bs[cur][row * 64 + (((fq + kk * 4) ^ (fm & 7)) * 8)]);
            }
            #pragma unroll
            for (int i = 0; i < 4; ++i)
                #pragma unroll
                for (int j = 0; j < 4; ++j)
                    acc[i][j] = __builtin_amdgcn_mfma_f32_16x16x32_bf16(af[i], bw[j], acc[i][j], 0, 0, 0);
        }
        __syncthreads();                               // one barrier per K-step
    }
    #pragma unroll
    for (int j = 0; j < 4; ++j) {
        const int col = n0 + wn + j * 16 + fm;
        const float bv = bias[col];
        #pragma unroll
        for (int i = 0; i < 4; ++i) {
            #pragma unroll
            for (int r = 0; r < 4; ++r) {
                const int row = m0 + wm + i * 16 + fq * 4 + r;
                const float v = acc[i][j][r] + bv;
                if (OUT_BF16)
                    ((__hip_bfloat16*)C)[(size_t)row * Ntot + col] = __float2bfloat16(v);
                else
                    ((float*)C)[(size_t)row * Ntot + col] = v;
            }
        }
    }
}

// ---------------- sparse attention (r7 form, validated) ----------------
#define P0DY ((2u)|(2u<<3)|(2u<<6)|(2u<<9)|(2u<<12)|(1u<<15)|(1u<<18)|(1u<<21))
#define P0DX ((2u)|(1u<<3)|(3u<<6)|(0u<<9)|(4u<<12)|(2u<<15)|(1u<<18)|(3u<<21))
#define P1DY ((3u)|(3u<<3)|(3u<<6)|(0u<<9)|(4u<<12)|(2u<<15)|(2u<<18)|(2u<<21))
#define P1DX ((2u)|(1u<<3)|(3u<<6)|(2u<<9)|(2u<<12)|(2u<<15)|(2u<<18)|(2u<<21))

__global__ __launch_bounds__(256) void attn_kernel(const __hip_bfloat16* __restrict__ qkv,
                                                   __hip_bfloat16* __restrict__ ctx) {
    const int t = blockIdx.x * 4 + (threadIdx.x >> 6);
    const int lane = threadIdx.x & 63;
    const int n  = lane >> 3;
    const int cg = lane & 7;
    const int x6 = t & 63;
    const int yq = (t >> 6) & 63;
    const int b  = t >> 12;
    const int side = x6 >> 5;
    const int x = x6 & 31;

    bool valid[2];
    size_t kb[2];
    #pragma unroll
    for (int p = 0; p < 2; ++p) {
        const unsigned dyp = p ? P1DY : P0DY;
        const unsigned dxp = p ? P1DX : P0DX;
        const int sh = 3 * n;
        const int dy = (int)((dyp >> sh) & 7) - 2;
        const int dx = (int)((dxp >> sh) & 7) - 2;
        const int yy = yq + dy, xx = x + dx;
        valid[p] = (p == 0 || n < 5) && yy >= 0 && yy < 64 && xx >= 0 && xx < 32;
        const int xm = side ? (31 - xx) : (63 - xx);
        int tm = (b << 12) + (yy << 6) + xm;
        if (!valid[p]) tm = t;
        kb[p] = (size_t)tm * 768 + 256 + cg * 8;
    }
    const size_t qb = (size_t)t * 768 + cg * 8;
    const size_t ob = (size_t)t * 256;

    #pragma unroll
    for (int hp = 0; hp < 2; ++hp) {
        bf16x8 q8[2], k8[2][2], v8[2][2];
        #pragma unroll
        for (int hh = 0; hh < 2; ++hh) {
            const int h = hp * 2 + hh;
            q8[hh] = *(const bf16x8*)(qkv + qb + h * 64);
            #pragma unroll
            for (int p = 0; p < 2; ++p) {
                k8[hh][p] = *(const bf16x8*)(qkv + kb[p] + h * 64);
                v8[hh][p] = *(const bf16x8*)(qkv + kb[p] + h * 64 + 256);
            }
        }
        #pragma unroll
        for (int hh = 0; hh < 2; ++hh) {
            float sc[2];
            #pragma unroll
            for (int p = 0; p < 2; ++p) {
                float s = 0.f;
                #pragma unroll
                for (int j = 0; j < 8; ++j) s += b2f(q8[hh][j]) * b2f(k8[hh][p][j]);
                s += __shfl_xor(s, 1, 64);
                s += __shfl_xor(s, 2, 64);
                s += __shfl_xor(s, 4, 64);
                sc[p] = valid[p] ? s * 0.125f : -1e30f;
            }
            const float p0 = __expf(sc[0]);
            const float p1 = __expf(sc[1]);
            float l = p0 + p1;
            l += __shfl_xor(l, 8, 64);
            l += __shfl_xor(l, 16, 64);
            l += __shfl_xor(l, 32, 64);

            float o[8];
            #pragma unroll
            for (int j = 0; j < 8; ++j)
                o[j] = p0 * b2f(v8[hh][0][j]) + p1 * b2f(v8[hh][1][j]);
            float r4[4];
            #pragma unroll
            for (int i = 0; i < 4; ++i) {
                const float a = o[2 * i], bb = o[2 * i + 1];
                const float mine = (n & 1) ? bb : a;
                const float theirs = (n & 1) ? a : bb;
                r4[i] = mine + __shfl_xor(theirs, 8, 64);
            }
            float r2[2];
            #pragma unroll
            for (int i = 0; i < 2; ++i) {
                const float a = r4[2 * i], bb = r4[2 * i + 1];
                const float mine = (n & 2) ? bb : a;
                const float theirs = (n & 2) ? a : bb;
                r2[i] = mine + __shfl_xor(theirs, 16, 64);
            }
            float ov;
            {
                const float a = r2[0], bb = r2[1];
                const float mine = (n & 4) ? bb : a;
                const float theirs = (n & 4) ? a : bb;
                ov = mine + __shfl_xor(theirs, 32, 64);
            }
            const float rl = __builtin_amdgcn_rcpf(l);
            ctx[ob + (hp * 2 + hh) * 64 + cg * 8 + n] = __float2bfloat16(ov * rl);
        }
    }
}

// ---------------- fused: ctx2 = ctx@out_w^T+out_b (in LDS), then proj+LN+ReLU+store ----------------
// r16: 512 thr / 8 waves (2M x 4N), M=64, grid 512. 2-phase dbuf B-staging (Bs0/Bs1, one
// sync per K-step). A-operands all LDS: ctx_s (phase A) -> Xs (phase B) in S0; c2s persists;
// g2/g3 fragments built in-register (elementwise |q-c2|, q*c2). LDS 128KB -> 1 block/CU.
__global__ __launch_bounds__(512, 2) void proj_ln_fused(const __hip_bfloat16* __restrict__ X,
                                                        const __hip_bfloat16* __restrict__ CTX,
                                                        const __hip_bfloat16* __restrict__ W2,
                                                        const float* __restrict__ out_b,
                                                        const __hip_bfloat16* __restrict__ W,
                                                        const float* __restrict__ bias,
                                                        const float* __restrict__ ln_g,
                                                        const float* __restrict__ ln_b,
                                                        float* __restrict__ out) {
    __shared__ __align__(16) short smem[65536];   // 128 KB
    __shared__ float mu_s[64], inv_s[64];
    short* S0  = smem;             // 16384: ctx_s (phase A), then Xs (phase B), then ys head
    short* c2s = smem + 16384;     // 16384: ctx2 tile, persists through phase B
    short* Bs0 = smem + 32768;     // 16384: B-slice buffer 0
    short* Bs1 = smem + 49152;     // 16384: B-slice buffer 1
    const int tid = threadIdx.x;
    const int m0 = blockIdx.x * 64;
    const int b = m0 >> 12, sp0 = m0 & 4095;
    const int wave = tid >> 6, lane = tid & 63;
    const int wmh = (wave >> 2) * 32;   // M-half
    const int wn  = (wave & 3) * 64;    // N-quarter
    const int fm = lane & 15;
    const int fq = lane >> 4;

    // ---- prologue: stage ctx_s (whole 64x256 tile) + W2 slice 0 into Bs0 ----
    #pragma unroll
    for (int v = 0; v < 4; ++v) {
        const int q = v * 512 + tid;
        const int r = q >> 5;              // row 0..63
        const int sl = q & 31;
        const int gc = (sl & 24) | ((sl & 7) ^ (r & 7));
        async_copy16(CTX + (size_t)(m0 + r) * 256 + gc * 8, &S0[(v * 512 + wave * 64) * 8]);
    }
    #pragma unroll
    for (int v = 0; v < 4; ++v) {
        const int q = v * 512 + tid;
        const int r = q >> 3;              // row 0..255
        const int cs = (q & 7) ^ (r & 7);
        async_copy16(W2 + (size_t)r * 256 + cs * 8, &Bs0[(v * 512 + wave * 64) * 8]);
    }
    __syncthreads();

    // ---- phase A: ctx2 = ctx @ out_w^T, 2-phase dbuf W2 slices ----
    f32x4 acc2[2][4] = {};
    #pragma unroll
    for (int t = 0; t < 4; ++t) {
        short* bsc = (t & 1) ? Bs1 : Bs0;
        short* bsn = (t & 1) ? Bs0 : Bs1;
        if (t < 3) {
            #pragma unroll
            for (int v = 0; v < 4; ++v) {
                const int q = v * 512 + tid;
                const int r = q >> 3;
                const int cs = (q & 7) ^ (r & 7);
                async_copy16(W2 + (size_t)r * 256 + (t + 1) * 64 + cs * 8, &bsn[(v * 512 + wave * 64) * 8]);
            }
        }
        #pragma unroll
        for (int kk = 0; kk < 2; ++kk) {
            const int jj = t * 8 + fq + kk * 4;
            bf16x8 af[2], bw[4];
            #pragma unroll
            for (int i = 0; i < 2; ++i) {
                const int row = wmh + i * 16 + fm;
                const int sl = (jj & 24) | ((jj & 7) ^ (row & 7));
                af[i] = *(const bf16x8*)(&S0[row * 256 + sl * 8]);
            }
            #pragma unroll
            for (int j = 0; j < 4; ++j) {
                const int row = wn + j * 16 + fm;
                bw[j] = *(const bf16x8*)(&bsc[row * 64 + (((fq + kk * 4) ^ (fm & 7)) * 8)]);
            }
            #pragma unroll
            for (int i = 0; i < 2; ++i)
                #pragma unroll
                for (int j = 0; j < 4; ++j)
                    acc2[i][j] = __builtin_amdgcn_mfma_f32_16x16x32_bf16(af[i], bw[j], acc2[i][j], 0, 0, 0);
        }
        __syncthreads();
    }

    // ---- transition: write c2s; restage S0 <- X tile; stage proj_w slice 0 into Bs0 ----
    #pragma unroll
    for (int j = 0; j < 4; ++j) {
        const int col = wn + j * 16 + fm;
        const float bv = out_b[col];
        const int jch = col >> 3, cl = col & 7;
        #pragma unroll
        for (int i = 0; i < 2; ++i)
            #pragma unroll
            for (int rr = 0; rr < 4; ++rr) {
                const int row = wmh + i * 16 + fq * 4 + rr;
                const int slot = (jch & 24) | ((jch & 7) ^ (row & 7));
                c2s[row * 256 + slot * 8 + cl] = f2b(acc2[i][j][rr] + bv);
            }
    }
    #pragma unroll
    for (int v = 0; v < 4; ++v) {
        const int q = v * 512 + tid;
        const int r = q >> 5;
        const int sl = q & 31;
        const int gc = (sl & 24) | ((sl & 7) ^ (r & 7));
        async_copy16(X + (size_t)(m0 + r) * 256 + gc * 8, &S0[(v * 512 + wave * 64) * 8]);
    }
    #pragma unroll
    for (int v = 0; v < 4; ++v) {
        const int q = v * 512 + tid;
        const int r = q >> 3;
        const int cs = (q & 7) ^ (r & 7);
        async_copy16(W + (size_t)r * 1024 + cs * 8, &Bs0[(v * 512 + wave * 64) * 8]);
    }
    __syncthreads();

    // ---- phase B: proj over K=1024 = [q | c2 | |q-c2| | q*c2], 16 K-steps, 2-phase dbuf ----
    f32x4 acc[2][4] = {};
    #pragma unroll
    for (int t = 0; t < 16; ++t) {
        short* bsc = (t & 1) ? Bs1 : Bs0;
        short* bsn = (t & 1) ? Bs0 : Bs1;
        if (t < 15) {
            #pragma unroll
            for (int v = 0; v < 4; ++v) {
                const int q = v * 512 + tid;
                const int r = q >> 3;
                const int cs = (q & 7) ^ (r & 7);
                async_copy16(W + (size_t)r * 1024 + (t + 1) * 64 + cs * 8, &bsn[(v * 512 + wave * 64) * 8]);
            }
        }
        const int g = t >> 2;
        #pragma unroll
        for (int kk = 0; kk < 2; ++kk) {
            const int jj = (t & 3) * 8 + fq + kk * 4;   // col-chunk 0..31 within 256
            bf16x8 af[2], bw[4];
            #pragma unroll
            for (int i = 0; i < 2; ++i) {
                const int row = wmh + i * 16 + fm;
                const int sl = (jj & 24) | ((jj & 7) ^ (row & 7));
                if (g == 0) {
                    af[i] = *(const bf16x8*)(&S0[row * 256 + sl * 8]);
                } else if (g == 1) {
                    af[i] = *(const bf16x8*)(&c2s[row * 256 + sl * 8]);
                } else {
                    const bf16x8 qe = *(const bf16x8*)(&S0[row * 256 + sl * 8]);
                    const bf16x8 ce = *(const bf16x8*)(&c2s[row * 256 + sl * 8]);
                    bf16x8 rr;
                    #pragma unroll
                    for (int e = 0; e < 8; ++e) {
                        const float a = b2f(qe[e]), c = b2f(ce[e]);
                        rr[e] = f2b(g == 2 ? fabsf(a - c) : a * c);
                    }
                    af[i] = rr;
                }
            }
            #pragma unroll
            for (int j = 0; j < 4; ++j) {
                const int row = wn + j * 16 + fm;
                bw[j] = *(const bf16x8*)(&bsc[row * 64 + (((fq + kk * 4) ^ (fm & 7)) * 8)]);
            }
            #pragma unroll
            for (int i = 0; i < 2; ++i)
                #pragma unroll
                for (int j = 0; j < 4; ++j)
                    acc[i][j] = __builtin_amdgcn_mfma_f32_16x16x32_bf16(af[i], bw[j], acc[i][j], 0, 0, 0);
        }
        __syncthreads();
    }

    // ---- epilogue: ys (bf16, stride 266) overlays S0/c2s (dead); LN; ReLU; store ----
    short* ys = smem;
    #pragma unroll
    for (int j = 0; j < 4; ++j) {
        const int col = wn + j * 16 + fm;
        const float bv = bias[col];
        #pragma unroll
        for (int i = 0; i < 2; ++i)
            #pragma unroll
            for (int r = 0; r < 4; ++r)
                ys[(wmh + i * 16 + fq * 4 + r) * 266 + col] = f2b(acc[i][j][r] + bv);
    }
    __syncthreads();
    {
        const int tt = tid >> 3, seg = tid & 7;   // 64 rows x 8 segs of 32
        float s = 0.f, ss = 0.f;
        #pragma unroll
        for (int j = 0; j < 32; ++j) {
            const float v = b2f(ys[tt * 266 + seg * 32 + j]);
            s += v; ss += v * v;
        }
        s += __shfl_xor(s, 1, 64);  ss += __shfl_xor(ss, 1, 64);
        s += __shfl_xor(s, 2, 64);  ss += __shfl_xor(ss, 2, 64);
        s += __shfl_xor(s, 4, 64);  ss += __shfl_xor(ss, 4, 64);
        if (seg == 0) {
            const float mu = s * (1.f / 256.f);
            const float var = ss * (1.f / 256.f) - mu * mu;
            mu_s[tt] = mu;
            inv_s[tt] = rsqrtf(var + 1e-5f);
        }
    }
    __syncthreads();
    {
        const int tl = tid & 63;
        const int j0 = tid >> 6;                  // 8 col-blocks of 32
        const float mu = mu_s[tl], inv = inv_s[tl];
        #pragma unroll
        for (int u = 0; u < 32; ++u) {
            const int j = j0 * 32 + u;
            const float v = (b2f(ys[tl * 266 + j]) - mu) * inv * ln_g[j] + ln_b[j];
            out[((size_t)(b * 256 + j) << 12) + sp0 + tl] = fmaxf(v, 0.f);
        }
    }
}

extern "C" void kernel_launch(void* const* d_in, const int* in_sizes, int n_in,
                              void* d_out, int out_size, void* d_ws, size_t ws_size,
                              hipStream_t stream) {
    (void)in_sizes; (void)n_in; (void)out_size; (void)ws_size;
    const float* feat   = (const float*)d_in[0];
    const float* in_w   = (const float*)d_in[1];
    const float* in_b   = (const float*)d_in[2];
    const float* out_w  = (const float*)d_in[3];
    const float* out_b  = (const float*)d_in[4];
    const float* proj_w = (const float*)d_in[5];
    const float* proj_b = (const float*)d_in[6];
    const float* ln_g   = (const float*)d_in[7];
    const float* ln_b   = (const float*)d_in[8];
    float* out = (float*)d_out;

    char* ws = (char*)d_ws;
    __hip_bfloat16* Xbf  = (__hip_bfloat16*)(ws);
    __hip_bfloat16* wbf  = (__hip_bfloat16*)(ws + (size_t)(16) * (1 << 20));
    __hip_bfloat16* qkv  = (__hip_bfloat16*)(ws + (size_t)(17) * (1 << 20));
    __hip_bfloat16* ctx  = (__hip_bfloat16*)(ws + (size_t)(65) * (1 << 20));
    __hip_bfloat16* in_wbf   = wbf;
    __hip_bfloat16* out_wbf  = wbf + 196608;
    __hip_bfloat16* proj_wbf = wbf + 262144;

    prep_kernel   <<<4352, 256, 0, stream>>>(feat, in_w, out_w, proj_w, Xbf, wbf);
    mfma_gemm<256, true><<<dim3(256, 6), 256, 0, stream>>>(Xbf, in_wbf, in_b, qkv, 768);
    attn_kernel   <<<NTOK / 4, 256, 0, stream>>>(qkv, ctx);
    proj_ln_fused <<<NTOK / 64, 512, 0, stream>>>(Xbf, ctx, out_wbf, out_b,
                                                  proj_wbf, proj_b, ln_g, ln_b, out);
}

// Round 5
// 180.844 us; speedup vs baseline: 1.3843x; 1.1123x over previous
//
#include <hip/hip_runtime.h>
#include <hip/hip_bf16.h>

// ContralateralAttention, round 17: consolidation. proj = round-1 form (best measured, ~40.5us).
// mfma_gemm = 2-phase dbuf (r16) + bijective XCD swizzle: 1D grid 1536, work=(bid&7)*192+(bid>>3),
// xb=work/6, yb=work%6 -> each XCD reuses 32 A-tiles (2MB) 6x from its L2.
// ws layout (MB): Xbf [0,16) | wbf [16,17) | qkv [17,65) | ctx [65,81)

#define NTOK 32768

using bf16x8 = __attribute__((ext_vector_type(8))) short;
using f32x4  = __attribute__((ext_vector_type(4))) float;

__device__ __forceinline__ float b2f(short s) {
    unsigned u = ((unsigned)(unsigned short)s) << 16;
    union { unsigned u; float f; } c; c.u = u; return c.f;
}
__device__ __forceinline__ short f2b(float f) {
    __hip_bfloat16 h = __float2bfloat16(f);
    return *(short*)&h;
}
__device__ __forceinline__ void async_copy16(const void* g, void* l) {
    __builtin_amdgcn_global_load_lds(
        (const __attribute__((address_space(1))) unsigned int*)g,
        (__attribute__((address_space(3))) unsigned int*)l, 16, 0, 0);
}

// ---------------- prep: vectorized feat transpose+cast AND weight casts ----------------
__global__ __launch_bounds__(256) void prep_kernel(const float* __restrict__ feat,
                                                   const float* __restrict__ in_w,
                                                   const float* __restrict__ out_w,
                                                   const float* __restrict__ proj_w,
                                                   __hip_bfloat16* __restrict__ X,
                                                   __hip_bfloat16* __restrict__ wbf) {
    const int bid = blockIdx.x;
    const int tid = threadIdx.x;
    if (bid < 4096) {
        __shared__ float tile[32][68];
        const int b   = bid >> 9;
        const int rem = bid & 511;
        const int sp0 = (rem & 63) * 64;
        const int c0  = (rem >> 6) * 32;
        #pragma unroll
        for (int u = 0; u < 2; ++u) {
            const int idx = tid + u * 256;      // 0..511
            const int cl = idx >> 4;            // 0..31
            const int sq = (idx & 15) * 4;      // 0..60
            const float4 v = *(const float4*)(feat + ((size_t)(b * 256 + c0 + cl) << 12) + sp0 + sq);
            tile[cl][sq]     = v.x;
            tile[cl][sq + 1] = v.y;
            tile[cl][sq + 2] = v.z;
            tile[cl][sq + 3] = v.w;
        }
        __syncthreads();
        #pragma unroll
        for (int u = 0; u < 2; ++u) {
            const int idx = tid + u * 256;      // 0..511
            const int tok = idx >> 3;           // 0..63
            const int cq  = (idx & 7) * 4;      // 0..28
            short4 s;
            s.x = f2b(tile[cq][tok]);
            s.y = f2b(tile[cq + 1][tok]);
            s.z = f2b(tile[cq + 2][tok]);
            s.w = f2b(tile[cq + 3][tok]);
            *(short4*)(X + (size_t)(b * 4096 + sp0 + tok) * 256 + c0 + cq) = s;
        }
    } else {
        const int i4 = (bid - 4096) * 1024 + tid * 4;
        if (i4 < 196608) {
            const float4 v = *(const float4*)(in_w + i4);
            short4 s = {f2b(v.x), f2b(v.y), f2b(v.z), f2b(v.w)};
            *(short4*)(wbf + i4) = s;
        }
        if (i4 < 65536) {
            const float4 v = *(const float4*)(out_w + i4);
            short4 s = {f2b(v.x), f2b(v.y), f2b(v.z), f2b(v.w)};
            *(short4*)(wbf + 196608 + i4) = s;
        }
        if (i4 < 262144) {
            const float4 v = *(const float4*)(proj_w + i4);
            short4 s = {f2b(v.x), f2b(v.y), f2b(v.z), f2b(v.w)};
            *(short4*)(wbf + 262144 + i4) = s;
        }
    }
}

// ---------------- MFMA GEMM (qkv): 256 thr, M=128 x N=128, BK=64, 2-phase dbuf ----------------
// 1D grid 1536, XCD-chunked work order: work=(bid&7)*192+(bid>>3); xb=work/6 (A-tile), yb=work%6.
template <int KDIM, bool OUT_BF16>
__global__ __launch_bounds__(256) void mfma_gemm(const __hip_bfloat16* __restrict__ A,
                                                 const __hip_bfloat16* __restrict__ W,
                                                 const float* __restrict__ bias,
                                                 void* __restrict__ C, int Ntot) {
    __shared__ __align__(16) short As[2][128 * 64];   // 2 x 16 KB
    __shared__ __align__(16) short Bs[2][128 * 64];   // 2 x 16 KB
    const int tid = threadIdx.x;
    const int work = (blockIdx.x & 7) * 192 + (blockIdx.x >> 3);
    const int m0 = (work / 6) * 128;
    const int n0 = (work % 6) * 128;
    const int wave = tid >> 6, lane = tid & 63;
    const int wm = (wave >> 1) * 64;
    const int wn = (wave & 1) * 64;
    const int fm = lane & 15;
    const int fq = lane >> 4;

    // prologue: stage K-slice 0 into buffer 0
    #pragma unroll
    for (int v = 0; v < 4; ++v) {
        const int qb = v * 256 + wave * 64;
        const int q = qb + lane;
        const int r = q >> 3;
        const int cs = (q & 7) ^ (r & 7);
        async_copy16(A + (size_t)(m0 + r) * KDIM + cs * 8, &As[0][qb * 8]);
        async_copy16(W + (size_t)(n0 + r) * KDIM + cs * 8, &Bs[0][qb * 8]);
    }
    __syncthreads();

    f32x4 acc[4][4] = {};
    #pragma unroll
    for (int t = 0; t < KDIM / 64; ++t) {
        const int cur = t & 1;
        if (t + 1 < KDIM / 64) {                       // issue next-slice stage FIRST
            #pragma unroll
            for (int v = 0; v < 4; ++v) {
                const int qb = v * 256 + wave * 64;
                const int q = qb + lane;
                const int r = q >> 3;
                const int cs = (q & 7) ^ (r & 7);
                async_copy16(A + (size_t)(m0 + r) * KDIM + (t + 1) * 64 + cs * 8, &As[cur ^ 1][qb * 8]);
                async_copy16(W + (size_t)(n0 + r) * KDIM + (t + 1) * 64 + cs * 8, &Bs[cur ^ 1][qb * 8]);
            }
        }
        #pragma unroll
        for (int kk = 0; kk < 2; ++kk) {
            bf16x8 af[4], bw[4];
            #pragma unroll
            for (int i = 0; i < 4; ++i) {
                const int row = wm + i * 16 + fm;
                af[i] = *(const bf16x8*)(&As[cur][row * 64 + (((fq + kk * 4) ^ (fm & 7)) * 8)]);
            }
            #pragma unroll
            for (int j = 0; j < 4; ++j) {
                const int row = wn + j * 16 + fm;
                bw[j] = *(const bf16x8*)(&Bs[cur][row * 64 + (((fq + kk * 4) ^ (fm & 7)) * 8)]);
            }
            #pragma unroll
            for (int i = 0; i < 4; ++i)
                #pragma unroll
                for (int j = 0; j < 4; ++j)
                    acc[i][j] = __builtin_amdgcn_mfma_f32_16x16x32_bf16(af[i], bw[j], acc[i][j], 0, 0, 0);
        }
        __syncthreads();                               // one barrier per K-step
    }
    #pragma unroll
    for (int j = 0; j < 4; ++j) {
        const int col = n0 + wn + j * 16 + fm;
        const float bv = bias[col];
        #pragma unroll
        for (int i = 0; i < 4; ++i) {
            #pragma unroll
            for (int r = 0; r < 4; ++r) {
                const int row = m0 + wm + i * 16 + fq * 4 + r;
                const float v = acc[i][j][r] + bv;
                if (OUT_BF16)
                    ((__hip_bfloat16*)C)[(size_t)row * Ntot + col] = __float2bfloat16(v);
                else
                    ((float*)C)[(size_t)row * Ntot + col] = v;
            }
        }
    }
}

// ---------------- sparse attention (r7 form, validated) ----------------
#define P0DY ((2u)|(2u<<3)|(2u<<6)|(2u<<9)|(2u<<12)|(1u<<15)|(1u<<18)|(1u<<21))
#define P0DX ((2u)|(1u<<3)|(3u<<6)|(0u<<9)|(4u<<12)|(2u<<15)|(1u<<18)|(3u<<21))
#define P1DY ((3u)|(3u<<3)|(3u<<6)|(0u<<9)|(4u<<12)|(2u<<15)|(2u<<18)|(2u<<21))
#define P1DX ((2u)|(1u<<3)|(3u<<6)|(2u<<9)|(2u<<12)|(2u<<15)|(2u<<18)|(2u<<21))

__global__ __launch_bounds__(256) void attn_kernel(const __hip_bfloat16* __restrict__ qkv,
                                                   __hip_bfloat16* __restrict__ ctx) {
    const int t = blockIdx.x * 4 + (threadIdx.x >> 6);
    const int lane = threadIdx.x & 63;
    const int n  = lane >> 3;
    const int cg = lane & 7;
    const int x6 = t & 63;
    const int yq = (t >> 6) & 63;
    const int b  = t >> 12;
    const int side = x6 >> 5;
    const int x = x6 & 31;

    bool valid[2];
    size_t kb[2];
    #pragma unroll
    for (int p = 0; p < 2; ++p) {
        const unsigned dyp = p ? P1DY : P0DY;
        const unsigned dxp = p ? P1DX : P0DX;
        const int sh = 3 * n;
        const int dy = (int)((dyp >> sh) & 7) - 2;
        const int dx = (int)((dxp >> sh) & 7) - 2;
        const int yy = yq + dy, xx = x + dx;
        valid[p] = (p == 0 || n < 5) && yy >= 0 && yy < 64 && xx >= 0 && xx < 32;
        const int xm = side ? (31 - xx) : (63 - xx);
        int tm = (b << 12) + (yy << 6) + xm;
        if (!valid[p]) tm = t;
        kb[p] = (size_t)tm * 768 + 256 + cg * 8;
    }
    const size_t qb = (size_t)t * 768 + cg * 8;
    const size_t ob = (size_t)t * 256;

    #pragma unroll
    for (int hp = 0; hp < 2; ++hp) {
        bf16x8 q8[2], k8[2][2], v8[2][2];
        #pragma unroll
        for (int hh = 0; hh < 2; ++hh) {
            const int h = hp * 2 + hh;
            q8[hh] = *(const bf16x8*)(qkv + qb + h * 64);
            #pragma unroll
            for (int p = 0; p < 2; ++p) {
                k8[hh][p] = *(const bf16x8*)(qkv + kb[p] + h * 64);
                v8[hh][p] = *(const bf16x8*)(qkv + kb[p] + h * 64 + 256);
            }
        }
        #pragma unroll
        for (int hh = 0; hh < 2; ++hh) {
            float sc[2];
            #pragma unroll
            for (int p = 0; p < 2; ++p) {
                float s = 0.f;
                #pragma unroll
                for (int j = 0; j < 8; ++j) s += b2f(q8[hh][j]) * b2f(k8[hh][p][j]);
                s += __shfl_xor(s, 1, 64);
                s += __shfl_xor(s, 2, 64);
                s += __shfl_xor(s, 4, 64);
                sc[p] = valid[p] ? s * 0.125f : -1e30f;
            }
            const float p0 = __expf(sc[0]);
            const float p1 = __expf(sc[1]);
            float l = p0 + p1;
            l += __shfl_xor(l, 8, 64);
            l += __shfl_xor(l, 16, 64);
            l += __shfl_xor(l, 32, 64);

            float o[8];
            #pragma unroll
            for (int j = 0; j < 8; ++j)
                o[j] = p0 * b2f(v8[hh][0][j]) + p1 * b2f(v8[hh][1][j]);
            float r4[4];
            #pragma unroll
            for (int i = 0; i < 4; ++i) {
                const float a = o[2 * i], bb = o[2 * i + 1];
                const float mine = (n & 1) ? bb : a;
                const float theirs = (n & 1) ? a : bb;
                r4[i] = mine + __shfl_xor(theirs, 8, 64);
            }
            float r2[2];
            #pragma unroll
            for (int i = 0; i < 2; ++i) {
                const float a = r4[2 * i], bb = r4[2 * i + 1];
                const float mine = (n & 2) ? bb : a;
                const float theirs = (n & 2) ? a : bb;
                r2[i] = mine + __shfl_xor(theirs, 16, 64);
            }
            float ov;
            {
                const float a = r2[0], bb = r2[1];
                const float mine = (n & 4) ? bb : a;
                const float theirs = (n & 4) ? a : bb;
                ov = mine + __shfl_xor(theirs, 32, 64);
            }
            const float rl = __builtin_amdgcn_rcpf(l);
            ctx[ob + (hp * 2 + hh) * 64 + cg * 8 + n] = __float2bfloat16(ov * rl);
        }
    }
}

// ---------------- fused: ctx2 = ctx@out_w^T+out_b (in LDS), then proj+LN+ReLU+store ----------------
// round-1 form verbatim (best measured): 512 thr / 8 waves (2M x 4N), M=64, BK=64, LDS 72KB.
__global__ __launch_bounds__(512, 4) void proj_ln_fused(const __hip_bfloat16* __restrict__ X,
                                                        const __hip_bfloat16* __restrict__ CTX,
                                                        const __hip_bfloat16* __restrict__ W2,
                                                        const float* __restrict__ out_b,
                                                        const __hip_bfloat16* __restrict__ W,
                                                        const float* __restrict__ bias,
                                                        const float* __restrict__ ln_g,
                                                        const float* __restrict__ ln_b,
                                                        float* __restrict__ out) {
    __shared__ __align__(16) short smem[36864];   // 72 KB
    __shared__ float mu_s[64], inv_s[64];
    short* c2s = smem;            // 64 x 256 (32 KB), persists through phase B
    short* As  = smem + 16384;    // 64 x 64 staging (8 KB)
    short* Bs  = smem + 20480;    // 256 x 64 staging (32 KB)
    const int tid = threadIdx.x;
    const int m0 = blockIdx.x * 64;
    const int b = m0 >> 12, sp0 = m0 & 4095;
    const int wave = tid >> 6, lane = tid & 63;
    const int wmh = (wave >> 2) * 32;   // M-half
    const int wn  = (wave & 3) * 64;    // N-quarter
    const int fm = lane & 15;
    const int fq = lane >> 4;

    // ---- phase A: ctx2 tile ----
    {
        f32x4 acc2[2][4] = {};
        for (int k0 = 0; k0 < 256; k0 += 64) {
            {   // ctx: 512 chunks, 1 per thread
                const int q = tid;
                const int r = q >> 3;
                const int cs = (q & 7) ^ (r & 7);
                async_copy16(CTX + (size_t)(m0 + r) * 256 + k0 + cs * 8, &As[(wave * 64) * 8]);
            }
            #pragma unroll
            for (int v = 0; v < 4; ++v) {          // out_w: 2048 chunks, 4 per thread
                const int q = v * 512 + tid;
                const int r = q >> 3;
                const int cs = (q & 7) ^ (r & 7);
                async_copy16(W2 + (size_t)r * 256 + k0 + cs * 8, &Bs[(v * 512 + wave * 64) * 8]);
            }
            __syncthreads();
            #pragma unroll
            for (int kk = 0; kk < 2; ++kk) {
                bf16x8 af[2], bw[4];
                #pragma unroll
                for (int i = 0; i < 2; ++i) {
                    const int row = wmh + i * 16 + fm;
                    af[i] = *(const bf16x8*)(&As[row * 64 + (((fq + kk * 4) ^ (fm & 7)) * 8)]);
                }
                #pragma unroll
                for (int j = 0; j < 4; ++j) {
                    const int row = wn + j * 16 + fm;
                    bw[j] = *(const bf16x8*)(&Bs[row * 64 + (((fq + kk * 4) ^ (fm & 7)) * 8)]);
                }
                #pragma unroll
                for (int i = 0; i < 2; ++i)
                    #pragma unroll
                    for (int j = 0; j < 4; ++j)
                        acc2[i][j] = __builtin_amdgcn_mfma_f32_16x16x32_bf16(af[i], bw[j], acc2[i][j], 0, 0, 0);
            }
            __syncthreads();
        }
        #pragma unroll
        for (int j = 0; j < 4; ++j) {
            const int col = wn + j * 16 + fm;
            const float bv = out_b[col];
            const int jch = col >> 3, cl = col & 7;
            #pragma unroll
            for (int i = 0; i < 2; ++i)
                #pragma unroll
                for (int rr = 0; rr < 4; ++rr) {
                    const int row = wmh + i * 16 + fq * 4 + rr;
                    const int slot = (jch & 24) | ((jch & 7) ^ (row & 7));
                    c2s[row * 256 + slot * 8 + cl] = f2b(acc2[i][j][rr] + bv);
                }
        }
    }
    __syncthreads();

    // ---- phase B: proj GEMM over K=1024 groups [q | c2 | |q-c2| | q*c2] ----
    f32x4 acc[2][4] = {};
    for (int k0 = 0; k0 < 1024; k0 += 64) {
        const int g = k0 >> 8;
        const int cb = k0 & 255;
        #pragma unroll
        for (int v = 0; v < 4; ++v) {              // proj_w: 2048 chunks, 4 per thread
            const int q = v * 512 + tid;
            const int r = q >> 3;
            const int cs = (q & 7) ^ (r & 7);
            async_copy16(W + (size_t)r * 1024 + k0 + cs * 8, &Bs[(v * 512 + wave * 64) * 8]);
        }
        if (g == 0) {
            const int q = tid;
            const int r = q >> 3;
            const int cs = (q & 7) ^ (r & 7);
            async_copy16(X + (size_t)(m0 + r) * 256 + cb + cs * 8, &As[(wave * 64) * 8]);
        } else if (g >= 2) {
            const int q = tid;
            const int r = q >> 3;
            const int cs = (q & 7) ^ (r & 7);
            int4 qraw = *(const int4*)(X + (size_t)(m0 + r) * 256 + cb + cs * 8);
            const int jch = (cb >> 3) + cs;
            const int slot = (jch & 24) | ((jch & 7) ^ (r & 7));
            int4 craw = *(const int4*)(&c2s[r * 256 + slot * 8]);
            const short* qs = (const short*)&qraw;
            const short* cw = (const short*)&craw;
            short tmp[8];
            #pragma unroll
            for (int j = 0; j < 8; ++j) {
                const float qv = b2f(qs[j]), cv = b2f(cw[j]);
                tmp[j] = f2b(g == 2 ? fabsf(qv - cv) : qv * cv);
            }
            *(int4*)(&As[q * 8]) = *(int4*)tmp;
        }
        // g == 1: no A staging — frags read straight from c2s
        __syncthreads();
        #pragma unroll
        for (int kk = 0; kk < 2; ++kk) {
            bf16x8 af[2], bw[4];
            if (g == 1) {
                #pragma unroll
                for (int i = 0; i < 2; ++i) {
                    const int row = wmh + i * 16 + fm;
                    const int jch = (cb >> 3) + fq + kk * 4;
                    const int slot = (jch & 24) | ((jch & 7) ^ (row & 7));
                    af[i] = *(const bf16x8*)(&c2s[row * 256 + slot * 8]);
                }
            } else {
                #pragma unroll
                for (int i = 0; i < 2; ++i) {
                    const int row = wmh + i * 16 + fm;
                    af[i] = *(const bf16x8*)(&As[row * 64 + (((fq + kk * 4) ^ (fm & 7)) * 8)]);
                }
            }
            #pragma unroll
            for (int j = 0; j < 4; ++j) {
                const int row = wn + j * 16 + fm;
                bw[j] = *(const bf16x8*)(&Bs[row * 64 + (((fq + kk * 4) ^ (fm & 7)) * 8)]);
            }
            #pragma unroll
            for (int i = 0; i < 2; ++i)
                #pragma unroll
                for (int j = 0; j < 4; ++j)
                    acc[i][j] = __builtin_amdgcn_mfma_f32_16x16x32_bf16(af[i], bw[j], acc[i][j], 0, 0, 0);
        }
        __syncthreads();
    }
    // ---- epilogue: ys (bf16, stride 266) overlays c2s/As (dead); LN; ReLU; store ----
    short* ys = smem;
    #pragma unroll
    for (int j = 0; j < 4; ++j) {
        const int col = wn + j * 16 + fm;
        const float bv = bias[col];
        #pragma unroll
        for (int i = 0; i < 2; ++i)
            #pragma unroll
            for (int r = 0; r < 4; ++r)
                ys[(wmh + i * 16 + fq * 4 + r) * 266 + col] = f2b(acc[i][j][r] + bv);
    }
    __syncthreads();
    {
        const int tt = tid >> 3, seg = tid & 7;   // 64 rows x 8 segs of 32
        float s = 0.f, ss = 0.f;
        #pragma unroll
        for (int j = 0; j < 32; ++j) {
            const float v = b2f(ys[tt * 266 + seg * 32 + j]);
            s += v; ss += v * v;
        }
        s += __shfl_xor(s, 1, 64);  ss += __shfl_xor(ss, 1, 64);
        s += __shfl_xor(s, 2, 64);  ss += __shfl_xor(ss, 2, 64);
        s += __shfl_xor(s, 4, 64);  ss += __shfl_xor(ss, 4, 64);
        if (seg == 0) {
            const float mu = s * (1.f / 256.f);
            const float var = ss * (1.f / 256.f) - mu * mu;
            mu_s[tt] = mu;
            inv_s[tt] = rsqrtf(var + 1e-5f);
        }
    }
    __syncthreads();
    {
        const int tl = tid & 63;
        const int j0 = tid >> 6;                  // 8 col-blocks of 32
        const float mu = mu_s[tl], inv = inv_s[tl];
        #pragma unroll
        for (int u = 0; u < 32; ++u) {
            const int j = j0 * 32 + u;
            const float v = (b2f(ys[tl * 266 + j]) - mu) * inv * ln_g[j] + ln_b[j];
            out[((size_t)(b * 256 + j) << 12) + sp0 + tl] = fmaxf(v, 0.f);
        }
    }
}

extern "C" void kernel_launch(void* const* d_in, const int* in_sizes, int n_in,
                              void* d_out, int out_size, void* d_ws, size_t ws_size,
                              hipStream_t stream) {
    (void)in_sizes; (void)n_in; (void)out_size; (void)ws_size;
    const float* feat   = (const float*)d_in[0];
    const float* in_w   = (const float*)d_in[1];
    const float* in_b   = (const float*)d_in[2];
    const float* out_w  = (const float*)d_in[3];
    const float* out_b  = (const float*)d_in[4];
    const float* proj_w = (const float*)d_in[5];
    const float* proj_b = (const float*)d_in[6];
    const float* ln_g   = (const float*)d_in[7];
    const float* ln_b   = (const float*)d_in[8];
    float* out = (float*)d_out;

    char* ws = (char*)d_ws;
    __hip_bfloat16* Xbf  = (__hip_bfloat16*)(ws);
    __hip_bfloat16* wbf  = (__hip_bfloat16*)(ws + (size_t)(16) * (1 << 20));
    __hip_bfloat16* qkv  = (__hip_bfloat16*)(ws + (size_t)(17) * (1 << 20));
    __hip_bfloat16* ctx  = (__hip_bfloat16*)(ws + (size_t)(65) * (1 << 20));
    __hip_bfloat16* in_wbf   = wbf;
    __hip_bfloat16* out_wbf  = wbf + 196608;
    __hip_bfloat16* proj_wbf = wbf + 262144;

    prep_kernel   <<<4352, 256, 0, stream>>>(feat, in_w, out_w, proj_w, Xbf, wbf);
    mfma_gemm<256, true><<<1536, 256, 0, stream>>>(Xbf, in_wbf, in_b, qkv, 768);
    attn_kernel   <<<NTOK / 4, 256, 0, stream>>>(qkv, ctx);
    proj_ln_fused <<<NTOK / 64, 512, 0, stream>>>(Xbf, ctx, out_wbf, out_b,
                                                  proj_wbf, proj_b, ln_g, ln_b, out);
}